// Round 1
// baseline (254.592 us; speedup 1.0000x reference)
//
#include <hip/hip_runtime.h>

#define BM 128
#define BN 128
#define BK 32

typedef __attribute__((ext_vector_type(4))) float f32x4;
typedef __attribute__((ext_vector_type(8))) short short8;

__device__ __forceinline__ unsigned short f2bf(float f) {
  unsigned int u = __float_as_uint(f);
  u += 0x7fff + ((u >> 16) & 1);   // round-to-nearest-even
  return (unsigned short)(u >> 16);
}

// ---------------- cast fp32 -> bf16 (stored as ushort), 4 elems/thread ----------------
__global__ __launch_bounds__(256) void cast_kernel(const float* __restrict__ in,
                                                   unsigned short* __restrict__ out,
                                                   int n4) {
  int i = blockIdx.x * 256 + threadIdx.x;
  if (i >= n4) return;
  float4 v = ((const float4*)in)[i];
  ushort4 o;
  o.x = f2bf(v.x); o.y = f2bf(v.y); o.z = f2bf(v.z); o.w = f2bf(v.w);
  ((ushort4*)out)[i] = o;
}

// ---------------- NT GEMM: C[m][n] = alpha * sum_k A[m][k] * B[n][k] ----------------
// A: [M][lda] bf16, B: [N][ldb] bf16. OutT = float (fp32 store) or unsigned short (bf16).
// TRANS_OUT: store C^T (Ct[n][m], ldc = leading dim of Ct) as packed bf16.
template <typename OutT, bool TRANS_OUT>
__global__ __launch_bounds__(256) void gemm_nt(const unsigned short* __restrict__ A, int lda,
                                               const unsigned short* __restrict__ B, int ldb,
                                               OutT* __restrict__ C, int ldc,
                                               int M, int N, int K, float alpha) {
  __shared__ __attribute__((aligned(16))) unsigned short As[BM * BK];
  __shared__ __attribute__((aligned(16))) unsigned short Bs[BN * BK];

  const int tid  = threadIdx.x;
  const int lane = tid & 63;
  const int wave = tid >> 6;
  const int bm = blockIdx.y * BM;
  const int bn = blockIdx.x * BN;
  const int wr = wave >> 1, wc = wave & 1;   // 2x2 waves, each 64x64 output

  f32x4 acc[4][4];
#pragma unroll
  for (int i = 0; i < 4; ++i)
#pragma unroll
    for (int j = 0; j < 4; ++j)
      acc[i][j] = (f32x4){0.f, 0.f, 0.f, 0.f};

  const unsigned short* gA = A + (size_t)bm * lda;
  const unsigned short* gB = B + (size_t)bn * ldb;

  const int srow = lane >> 2;          // 0..15 within 16-row chunk
  const int scol = (lane & 3) * 8;     // 0,8,16,24

  for (int k0 = 0; k0 < K; k0 += BK) {
    __syncthreads();
#pragma unroll
    for (int i = 0; i < 2; ++i) {
      const int chunk = i * 4 + wave;            // 0..7, each = 16 rows x 32 cols
      const int row = chunk * 16 + srow;
      __builtin_amdgcn_global_load_lds(
          (const __attribute__((address_space(1))) void*)(gA + (size_t)row * lda + k0 + scol),
          (__attribute__((address_space(3))) void*)(As + chunk * 512 + lane * 8),
          16, 0, 0);
      __builtin_amdgcn_global_load_lds(
          (const __attribute__((address_space(1))) void*)(gB + (size_t)row * ldb + k0 + scol),
          (__attribute__((address_space(3))) void*)(Bs + chunk * 512 + lane * 8),
          16, 0, 0);
    }
    __syncthreads();

    short8 a[4], b[4];
#pragma unroll
    for (int mi = 0; mi < 4; ++mi)
      a[mi] = *(const short8*)&As[(wr * 64 + mi * 16 + (lane & 15)) * BK + (lane >> 4) * 8];
#pragma unroll
    for (int ni = 0; ni < 4; ++ni)
      b[ni] = *(const short8*)&Bs[(wc * 64 + ni * 16 + (lane & 15)) * BK + (lane >> 4) * 8];

#pragma unroll
    for (int mi = 0; mi < 4; ++mi)
#pragma unroll
      for (int ni = 0; ni < 4; ++ni)
        acc[mi][ni] = __builtin_amdgcn_mfma_f32_16x16x32_bf16(a[mi], b[ni], acc[mi][ni], 0, 0, 0);
  }

  // epilogue: C/D layout col = lane&15, row = (lane>>4)*4 + reg
  const int c_col  = lane & 15;
  const int c_row4 = (lane >> 4) * 4;
#pragma unroll
  for (int mi = 0; mi < 4; ++mi) {
#pragma unroll
    for (int ni = 0; ni < 4; ++ni) {
      const int grow0 = bm + wr * 64 + mi * 16 + c_row4;
      const int gcol  = bn + wc * 64 + ni * 16 + c_col;
      if constexpr (TRANS_OUT) {
        ushort4 o;
        o.x = f2bf(acc[mi][ni][0] * alpha);
        o.y = f2bf(acc[mi][ni][1] * alpha);
        o.z = f2bf(acc[mi][ni][2] * alpha);
        o.w = f2bf(acc[mi][ni][3] * alpha);
        *(ushort4*)((unsigned short*)C + (size_t)gcol * ldc + grow0) = o;
      } else {
#pragma unroll
        for (int j = 0; j < 4; ++j) {
          const float v = acc[mi][ni][j] * alpha;
          if constexpr (sizeof(OutT) == 4) {
            C[(size_t)(grow0 + j) * ldc + gcol] = v;
          } else {
            C[(size_t)(grow0 + j) * ldc + gcol] = (OutT)f2bf(v);
          }
        }
      }
    }
  }
}

// ---------------- row softmax over S (fp32 [4096][4096]); writes bf16 P in place ----------------
// P row r lives at bytes [r*16384, r*16384 + 8192) of the S buffer (elem stride 8192 bf16).
__global__ __launch_bounds__(256) void softmax_rows(float* __restrict__ S) {
  const int row  = blockIdx.x;
  const int t    = threadIdx.x;
  const int lane = t & 63;
  const int wave = t >> 6;

  const float4* src = (const float4*)(S + (size_t)row * 4096);
  float4 v[4];
  float m = -3.0e38f;
#pragma unroll
  for (int i = 0; i < 4; ++i) {
    v[i] = src[t + 256 * i];
    m = fmaxf(m, fmaxf(fmaxf(v[i].x, v[i].y), fmaxf(v[i].z, v[i].w)));
  }
#pragma unroll
  for (int off = 1; off < 64; off <<= 1)
    m = fmaxf(m, __shfl_xor(m, off));

  __shared__ float red[4];
  if (lane == 0) red[wave] = m;
  __syncthreads();
  m = fmaxf(fmaxf(red[0], red[1]), fmaxf(red[2], red[3]));
  __syncthreads();

  float p[16];
  float s = 0.f;
#pragma unroll
  for (int i = 0; i < 4; ++i) {
    p[4 * i + 0] = __expf(v[i].x - m);
    p[4 * i + 1] = __expf(v[i].y - m);
    p[4 * i + 2] = __expf(v[i].z - m);
    p[4 * i + 3] = __expf(v[i].w - m);
    s += p[4 * i + 0] + p[4 * i + 1] + p[4 * i + 2] + p[4 * i + 3];
  }
#pragma unroll
  for (int off = 1; off < 64; off <<= 1)
    s += __shfl_xor(s, off);
  if (lane == 0) red[wave] = s;
  __syncthreads();
  s = red[0] + red[1] + red[2] + red[3];
  const float inv = 1.0f / s;

  unsigned short* dst = (unsigned short*)S + (size_t)row * 8192;
#pragma unroll
  for (int i = 0; i < 4; ++i) {
    ushort4 o;
    o.x = f2bf(p[4 * i + 0] * inv);
    o.y = f2bf(p[4 * i + 1] * inv);
    o.z = f2bf(p[4 * i + 2] * inv);
    o.w = f2bf(p[4 * i + 3] * inv);
    *(ushort4*)(dst + 4 * (t + 256 * i)) = o;
  }
}

// ---------------- launch ----------------
extern "C" void kernel_launch(void* const* d_in, const int* in_sizes, int n_in,
                              void* d_out, int out_size, void* d_ws, size_t ws_size,
                              hipStream_t stream) {
  const float* x  = (const float*)d_in[0];
  const float* Wq = (const float*)d_in[1];
  const float* Wk = (const float*)d_in[2];
  const float* Wv = (const float*)d_in[3];

  const int SEQ = 4096, DIN = 1024, DOUT = 1024;

  // workspace layout (bytes):
  //   [0, 64MB)      : S fp32 [4096][4096]; after softmax, P bf16 in place (row stride 8192 elems)
  //   [64MB, ...)    : xb, qb, kb, vT (bf16, 8MB each), Wq/Wk/Wv bf16 (2MB each)  => ~102MB total
  char* ws = (char*)d_ws;
  float*          S   = (float*)ws;
  unsigned short* Pm  = (unsigned short*)ws;                 // bf16 view, row stride 8192
  unsigned short* xb  = (unsigned short*)(ws + 67108864);
  unsigned short* qb  = xb + 4194304;
  unsigned short* kb  = qb + 4194304;
  unsigned short* vT  = kb + 4194304;                        // [DOUT][SEQ]
  unsigned short* wqb = vT + 4194304;
  unsigned short* wkb = wqb + 1048576;
  unsigned short* wvb = wkb + 1048576;

  cast_kernel<<<4096, 256, 0, stream>>>(x,  xb,  1048576);
  cast_kernel<<<1024, 256, 0, stream>>>(Wq, wqb, 262144);
  cast_kernel<<<1024, 256, 0, stream>>>(Wk, wkb, 262144);
  cast_kernel<<<1024, 256, 0, stream>>>(Wv, wvb, 262144);

  const dim3 blk(256);
  // q = x @ Wq^T, k = x @ Wk^T  (bf16 out)
  gemm_nt<unsigned short, false><<<dim3(DOUT / BN, SEQ / BM), blk, 0, stream>>>(
      xb, DIN, wqb, DIN, qb, DOUT, SEQ, DOUT, DIN, 1.0f);
  gemm_nt<unsigned short, false><<<dim3(DOUT / BN, SEQ / BM), blk, 0, stream>>>(
      xb, DIN, wkb, DIN, kb, DOUT, SEQ, DOUT, DIN, 1.0f);
  // vT[d][s] = (x @ Wv^T)[s][d]  (transposed bf16 store)
  gemm_nt<unsigned short, true><<<dim3(DOUT / BN, SEQ / BM), blk, 0, stream>>>(
      xb, DIN, wvb, DIN, vT, SEQ, SEQ, DOUT, DIN, 1.0f);
  // S = (q @ k^T) / 32  (fp32)
  gemm_nt<float, false><<<dim3(SEQ / BN, SEQ / BM), blk, 0, stream>>>(
      qb, DOUT, kb, DOUT, S, SEQ, SEQ, SEQ, DIN, 0.03125f);
  // row softmax, bf16 P in place
  softmax_rows<<<SEQ, 256, 0, stream>>>(S);
  // context = P @ vT^T  -> d_out fp32
  gemm_nt<float, false><<<dim3(DOUT / BN, SEQ / BM), blk, 0, stream>>>(
      Pm, 8192, vT, SEQ, (float*)d_out, DOUT, SEQ, DOUT, SEQ, 1.0f);
}

// Round 2
// 201.950 us; speedup vs baseline: 1.2607x; 1.2607x over previous
//
#include <hip/hip_runtime.h>

#define BM 128
#define BN 128
#define BK 32

typedef __attribute__((ext_vector_type(4))) float f32x4;
typedef __attribute__((ext_vector_type(8))) short short8;

__device__ __forceinline__ unsigned short f2bf(float f) {
  unsigned int u = __float_as_uint(f);
  u += 0x7fff + ((u >> 16) & 1);   // round-to-nearest-even
  return (unsigned short)(u >> 16);
}

// ---------------- cast fp32 -> bf16 (stored as ushort), 4 elems/thread ----------------
__global__ __launch_bounds__(256) void cast_kernel(const float* __restrict__ in,
                                                   unsigned short* __restrict__ out,
                                                   int n4) {
  int i = blockIdx.x * 256 + threadIdx.x;
  if (i >= n4) return;
  float4 v = ((const float4*)in)[i];
  ushort4 o;
  o.x = f2bf(v.x); o.y = f2bf(v.y); o.z = f2bf(v.z); o.w = f2bf(v.w);
  ((ushort4*)out)[i] = o;
}

// ---------------- NT GEMM: C[m][n] = alpha * sum_k A[m][k] * B[n][k] ----------------
// MODE 0: fp32 output; blockIdx.z selects K-chunk [z*ksplit, (z+1)*ksplit) and
//         output buffer (z=0 -> C0, z=1 -> C1) for split-K partials.
// MODE 2: QKV fused epilogue; bf16. cols [0,2048) -> Cqk (packed q|k), cols
//         [2048,3072) -> transposed store into CvT[col-2048][row].
template <int MODE>
__global__ __launch_bounds__(256) void gemm_nt(
    const unsigned short* __restrict__ A, int lda,
    const unsigned short* __restrict__ B, int ldb,
    int ksplit, float alpha,
    float* __restrict__ C0, float* __restrict__ C1, int ldc,
    unsigned short* __restrict__ Cqk, int ldqk,
    unsigned short* __restrict__ CvT, int ldvt) {
  __shared__ __attribute__((aligned(16))) unsigned short As[BM * BK];
  __shared__ __attribute__((aligned(16))) unsigned short Bs[BN * BK];

  const int tid  = threadIdx.x;
  const int lane = tid & 63;
  const int wave = tid >> 6;

  // XCD-aware bijective swizzle over (x,y); all our 2D grids have nwg % 8 == 0.
  const int nx   = gridDim.x;
  const int nwg  = nx * gridDim.y;
  const int orig = blockIdx.y * nx + blockIdx.x;
  const int cpx  = nwg >> 3;
  const int wg   = (orig & 7) * cpx + (orig >> 3);
  const int bm   = (wg / nx) * BM;
  const int bn   = (wg % nx) * BN;

  const int kbeg = blockIdx.z * ksplit;
  const int kend = kbeg + ksplit;

  const int wr = wave >> 1, wc = wave & 1;   // 2x2 waves, each 64x64 output

  f32x4 acc[4][4];
#pragma unroll
  for (int i = 0; i < 4; ++i)
#pragma unroll
    for (int j = 0; j < 4; ++j)
      acc[i][j] = (f32x4){0.f, 0.f, 0.f, 0.f};

  const unsigned short* gA = A + (size_t)bm * lda;
  const unsigned short* gB = B + (size_t)bn * ldb;

  const int srow = lane >> 2;          // 0..15 within 16-row chunk
  const int scol = (lane & 3) * 8;     // 0,8,16,24

  for (int k0 = kbeg; k0 < kend; k0 += BK) {
    __syncthreads();
#pragma unroll
    for (int i = 0; i < 2; ++i) {
      const int chunk = i * 4 + wave;            // 0..7, each = 16 rows x 32 cols
      const int row = chunk * 16 + srow;
      __builtin_amdgcn_global_load_lds(
          (const __attribute__((address_space(1))) void*)(gA + (size_t)row * lda + k0 + scol),
          (__attribute__((address_space(3))) void*)(As + chunk * 512 + lane * 8),
          16, 0, 0);
      __builtin_amdgcn_global_load_lds(
          (const __attribute__((address_space(1))) void*)(gB + (size_t)row * ldb + k0 + scol),
          (__attribute__((address_space(3))) void*)(Bs + chunk * 512 + lane * 8),
          16, 0, 0);
    }
    __syncthreads();

    short8 a[4], b[4];
#pragma unroll
    for (int mi = 0; mi < 4; ++mi)
      a[mi] = *(const short8*)&As[(wr * 64 + mi * 16 + (lane & 15)) * BK + (lane >> 4) * 8];
#pragma unroll
    for (int ni = 0; ni < 4; ++ni)
      b[ni] = *(const short8*)&Bs[(wc * 64 + ni * 16 + (lane & 15)) * BK + (lane >> 4) * 8];

#pragma unroll
    for (int mi = 0; mi < 4; ++mi)
#pragma unroll
      for (int ni = 0; ni < 4; ++ni)
        acc[mi][ni] = __builtin_amdgcn_mfma_f32_16x16x32_bf16(a[mi], b[ni], acc[mi][ni], 0, 0, 0);
  }

  // epilogue: C/D layout col = lane&15, row = (lane>>4)*4 + reg
  const int c_col  = lane & 15;
  const int c_row4 = (lane >> 4) * 4;
#pragma unroll
  for (int mi = 0; mi < 4; ++mi) {
#pragma unroll
    for (int ni = 0; ni < 4; ++ni) {
      const int grow0 = bm + wr * 64 + mi * 16 + c_row4;
      const int gcol  = bn + wc * 64 + ni * 16 + c_col;
      if constexpr (MODE == 0) {
        float* __restrict__ C = blockIdx.z ? C1 : C0;
#pragma unroll
        for (int j = 0; j < 4; ++j)
          C[(size_t)(grow0 + j) * ldc + gcol] = acc[mi][ni][j] * alpha;
      } else {
        if (bn < 2048) {
#pragma unroll
          for (int j = 0; j < 4; ++j)
            Cqk[(size_t)(grow0 + j) * ldqk + gcol] = f2bf(acc[mi][ni][j] * alpha);
        } else {
          ushort4 o;
          o.x = f2bf(acc[mi][ni][0] * alpha);
          o.y = f2bf(acc[mi][ni][1] * alpha);
          o.z = f2bf(acc[mi][ni][2] * alpha);
          o.w = f2bf(acc[mi][ni][3] * alpha);
          *(ushort4*)(CvT + (size_t)(gcol - 2048) * ldvt + grow0) = o;
        }
      }
    }
  }
}

// ---------------- row softmax over S (fp32 [4096][4096]); writes bf16 P in place ----------------
// P row r lives at bytes [r*16384, r*16384 + 8192) of the S buffer (elem stride 8192 bf16).
__global__ __launch_bounds__(256) void softmax_rows(float* __restrict__ S) {
  const int row  = blockIdx.x;
  const int t    = threadIdx.x;
  const int lane = t & 63;
  const int wave = t >> 6;

  const float4* src = (const float4*)(S + (size_t)row * 4096);
  float4 v[4];
  float m = -3.0e38f;
#pragma unroll
  for (int i = 0; i < 4; ++i) {
    v[i] = src[t + 256 * i];
    m = fmaxf(m, fmaxf(fmaxf(v[i].x, v[i].y), fmaxf(v[i].z, v[i].w)));
  }
#pragma unroll
  for (int off = 1; off < 64; off <<= 1)
    m = fmaxf(m, __shfl_xor(m, off));

  __shared__ float red[4];
  if (lane == 0) red[wave] = m;
  __syncthreads();
  m = fmaxf(fmaxf(red[0], red[1]), fmaxf(red[2], red[3]));
  __syncthreads();

  float p[16];
  float s = 0.f;
#pragma unroll
  for (int i = 0; i < 4; ++i) {
    p[4 * i + 0] = __expf(v[i].x - m);
    p[4 * i + 1] = __expf(v[i].y - m);
    p[4 * i + 2] = __expf(v[i].z - m);
    p[4 * i + 3] = __expf(v[i].w - m);
    s += p[4 * i + 0] + p[4 * i + 1] + p[4 * i + 2] + p[4 * i + 3];
  }
#pragma unroll
  for (int off = 1; off < 64; off <<= 1)
    s += __shfl_xor(s, off);
  if (lane == 0) red[wave] = s;
  __syncthreads();
  s = red[0] + red[1] + red[2] + red[3];
  const float inv = 1.0f / s;

  unsigned short* dst = (unsigned short*)S + (size_t)row * 8192;
#pragma unroll
  for (int i = 0; i < 4; ++i) {
    ushort4 o;
    o.x = f2bf(p[4 * i + 0] * inv);
    o.y = f2bf(p[4 * i + 1] * inv);
    o.z = f2bf(p[4 * i + 2] * inv);
    o.w = f2bf(p[4 * i + 3] * inv);
    *(ushort4*)(dst + 4 * (t + 256 * i)) = o;
  }
}

// ---------------- combine split-K partials: out += p ----------------
__global__ __launch_bounds__(256) void add_kernel(float* __restrict__ out,
                                                  const float* __restrict__ p, int n4) {
  int i = blockIdx.x * 256 + threadIdx.x;
  if (i >= n4) return;
  float4 a = ((const float4*)out)[i];
  float4 b = ((const float4*)p)[i];
  a.x += b.x; a.y += b.y; a.z += b.z; a.w += b.w;
  ((float4*)out)[i] = a;
}

// ---------------- launch ----------------
extern "C" void kernel_launch(void* const* d_in, const int* in_sizes, int n_in,
                              void* d_out, int out_size, void* d_ws, size_t ws_size,
                              hipStream_t stream) {
  const float* x  = (const float*)d_in[0];
  const float* Wq = (const float*)d_in[1];
  const float* Wk = (const float*)d_in[2];
  const float* Wv = (const float*)d_in[3];

  // workspace layout (bytes):
  //   [0, 64M)        : S fp32 [4096][4096]; after softmax, P bf16 in place (row stride 8192)
  //   [64M, 80M)      : QK bf16 [4096][2048] (q | k packed); later reused as ctx
  //                     split-K chunk-1 partial fp32 [4096][1024] (same 16.78 MB)
  //   [80M, 88M)      : vT bf16 [1024][4096]
  //   [88M, 96M)      : xb bf16 [4096][1024]
  //   [96M, 102M)     : Wcat bf16 [3072][1024] (Wq | Wk | Wv stacked)
  char* ws = (char*)d_ws;
  float*          S     = (float*)ws;
  unsigned short* Pm    = (unsigned short*)ws;                  // bf16 view, row stride 8192
  unsigned short* QK    = (unsigned short*)(ws + 67108864);
  float*          Cpart = (float*)(ws + 67108864);              // reuse after scores GEMM
  unsigned short* vT    = (unsigned short*)(ws + 83886080);     // [1024][4096]
  unsigned short* xb    = (unsigned short*)(ws + 92274688);
  unsigned short* Wcat  = (unsigned short*)(ws + 100663296);

  cast_kernel<<<4096, 256, 0, stream>>>(x,  xb,            1048576);
  cast_kernel<<<1024, 256, 0, stream>>>(Wq, Wcat,           262144);
  cast_kernel<<<1024, 256, 0, stream>>>(Wk, Wcat + 1048576, 262144);
  cast_kernel<<<1024, 256, 0, stream>>>(Wv, Wcat + 2097152, 262144);

  // fused QKV: [4096][3072] = xb @ Wcat^T; q|k -> QK (bf16), v -> vT (transposed bf16)
  gemm_nt<2><<<dim3(24, 32, 1), 256, 0, stream>>>(
      xb, 1024, Wcat, 1024, 1024, 1.0f,
      nullptr, nullptr, 0, QK, 2048, vT, 4096);

  // S = (q @ k^T) / 32  (fp32)
  gemm_nt<0><<<dim3(32, 32, 1), 256, 0, stream>>>(
      QK, 2048, QK + 1024, 2048, 1024, 0.03125f,
      S, S, 4096, nullptr, 0, nullptr, 0);

  // row softmax, bf16 P in place
  softmax_rows<<<4096, 256, 0, stream>>>(S);

  // context = P @ vT^T, split-K=2 (z=0 -> d_out, z=1 -> Cpart), then combine
  gemm_nt<0><<<dim3(8, 32, 2), 256, 0, stream>>>(
      Pm, 8192, vT, 4096, 2048, 1.0f,
      (float*)d_out, Cpart, 1024, nullptr, 0, nullptr, 0);
  add_kernel<<<4096, 256, 0, stream>>>((float*)d_out, Cpart, 1048576);
}

// Round 3
// 171.607 us; speedup vs baseline: 1.4836x; 1.1768x over previous
//
#include <hip/hip_runtime.h>

typedef __attribute__((ext_vector_type(4))) float f32x4;
typedef __attribute__((ext_vector_type(8))) short short8;

__device__ __forceinline__ unsigned short f2bf(float f) {
  unsigned int u = __float_as_uint(f);
  u += 0x7fff + ((u >> 16) & 1);   // round-to-nearest-even
  return (unsigned short)(u >> 16);
}

// ---------------- cast fp32 -> bf16 (stored as ushort), 4 elems/thread ----------------
__global__ __launch_bounds__(256) void cast_kernel(const float* __restrict__ in,
                                                   unsigned short* __restrict__ out,
                                                   int n4) {
  int i = blockIdx.x * 256 + threadIdx.x;
  if (i >= n4) return;
  float4 v = ((const float4*)in)[i];
  ushort4 o;
  o.x = f2bf(v.x); o.y = f2bf(v.y); o.z = f2bf(v.z); o.w = f2bf(v.w);
  ((ushort4*)out)[i] = o;
}

// ======================= 256x256 8-phase NT GEMM (m201 template) =======================
// C[m][n] = alpha * sum_k A[m][k]*B[n][k].  8 waves (2M x 4N), BK=64, 128KB LDS dbuf,
// st_16x32 swizzle (linear gload_lds dest + inverse-swizzled global src + swizzled read).
// MODE 0: fp32 out, blockIdx.z in [0,4) selects K-chunk and (C0..C3, ldc0..3).
// MODE 2: QKV epilogue: cols [0,2048) -> bf16 Cqk; cols [2048,3072) -> transposed CvT.

#define PHASE(M0, STAGE, TAILWAIT)                                            \
  {                                                                           \
    _Pragma("unroll")                                                         \
    for (int mi = 0; mi < 2; ++mi) {                                          \
      _Pragma("unroll")                                                       \
      for (int ks = 0; ks < 2; ++ks) {                                        \
        const int row = (M0 + mi) * 16 + frow;                                \
        const int e = (row * 64 + ks * 32 + fk) ^ (((row >> 2) & 1) << 4);    \
        af[mi][ks] = *(const short8*)(Acur + e);                              \
      }                                                                       \
    }                                                                         \
    STAGE;                                                                    \
    __builtin_amdgcn_s_barrier();                                             \
    asm volatile("s_waitcnt lgkmcnt(0)" ::: "memory");                        \
    __builtin_amdgcn_sched_barrier(0);                                        \
    __builtin_amdgcn_s_setprio(1);                                            \
    _Pragma("unroll")                                                         \
    for (int mi = 0; mi < 2; ++mi)                                            \
      _Pragma("unroll")                                                       \
      for (int n = 0; n < 4; ++n)                                             \
        _Pragma("unroll")                                                     \
        for (int ks = 0; ks < 2; ++ks)                                        \
          acc[M0 + mi][n] = __builtin_amdgcn_mfma_f32_16x16x32_bf16(          \
              af[mi][ks], bf[n][ks], acc[M0 + mi][n], 0, 0, 0);               \
    __builtin_amdgcn_s_setprio(0);                                            \
    __builtin_amdgcn_sched_barrier(0);                                        \
    TAILWAIT;                                                                 \
    __builtin_amdgcn_s_barrier();                                             \
  }

template <int MODE>
__global__ __launch_bounds__(512, 2) void gemm8(
    const unsigned short* __restrict__ A, int lda,
    const unsigned short* __restrict__ B, int ldb,
    int ksplit, float alpha,
    float* __restrict__ C0, int ldc0, float* __restrict__ C1, int ldc1,
    float* __restrict__ C2, int ldc2, float* __restrict__ C3, int ldc3,
    unsigned short* __restrict__ Cqk, int ldqk,
    unsigned short* __restrict__ CvT, int ldvt) {
  // 128 KB: buf b at b*32768 (ushorts); A halves at +0,+8192; B halves at +16384,+24576
  __shared__ __attribute__((aligned(16))) unsigned short lds[65536];

  const int t    = threadIdx.x;
  const int lane = t & 63;
  const int wave = t >> 6;
  const int wr   = wave >> 2;        // 0..1  (M)
  const int wc   = wave & 3;         // 0..3  (N)

  // XCD-aware bijective swizzle on the xy plane (nwg % 8 == 0 for all our grids)
  const int nx   = gridDim.x;
  const int nwg  = nx * gridDim.y;
  const int orig = blockIdx.y * nx + blockIdx.x;
  const int wg   = (orig & 7) * (nwg >> 3) + (orig >> 3);
  const int bm   = (wg / nx) * 256;
  const int bn   = (wg % nx) * 256;

  const int kbeg = blockIdx.z * ksplit;
  const int NT   = ksplit >> 6;

  const unsigned short* gA = A + (size_t)bm * lda;
  const unsigned short* gB = B + (size_t)bn * ldb;

  // stage one 128x64 half-tile: linear LDS dest (t*16B + j*8KB), inverse-swizzled source
  auto stage = [&](const unsigned short* gbase, int ld, int k0, unsigned short* dst) {
#pragma unroll
    for (int j = 0; j < 2; ++j) {
      const int de = t * 8 + j * 4096;                 // dest elem within half (linear)
      const int se = de ^ (((t >> 5) & 1) << 4);       // pre-swizzled source elem
      __builtin_amdgcn_global_load_lds(
          (const __attribute__((address_space(1))) void*)(gbase + (size_t)(se >> 6) * ld + k0 + (se & 63)),
          (__attribute__((address_space(3))) void*)(dst + de),
          16, 0, 0);
    }
  };

  f32x4 acc[8][4];
#pragma unroll
  for (int i = 0; i < 8; ++i)
#pragma unroll
    for (int j = 0; j < 4; ++j)
      acc[i][j] = (f32x4){0.f, 0.f, 0.f, 0.f};

  const int frow = lane & 15;
  const int fk   = (lane >> 4) * 8;

  // ---- prologue: K-tile 0 (A0,A1,B0,B1) + K-tile 1's B halves; leave B(1) in flight ----
  stage(gA,                     lda, kbeg, lds);
  stage(gA + (size_t)128 * lda, lda, kbeg, lds + 8192);
  stage(gB,                     ldb, kbeg, lds + 16384);
  stage(gB + (size_t)128 * ldb, ldb, kbeg, lds + 24576);
  if (NT > 1) {
    stage(gB,                     ldb, kbeg + 64, lds + 32768 + 16384);
    stage(gB + (size_t)128 * ldb, ldb, kbeg + 64, lds + 32768 + 24576);
    asm volatile("s_waitcnt vmcnt(4)" ::: "memory");
  } else {
    asm volatile("s_waitcnt vmcnt(0)" ::: "memory");
  }
  __builtin_amdgcn_sched_barrier(0);
  __builtin_amdgcn_s_barrier();

  for (int u = 0; u < NT; ++u) {
    const int cur = u & 1, nxt = cur ^ 1;
    const unsigned short* Acur = lds + cur * 32768 + wr * 8192;
    const unsigned short* Bcur = lds + cur * 32768 + 16384 + (wc >> 1) * 8192;
    const int brow0 = (wc & 1) * 64;

    short8 bf[4][2];
    short8 af[2][2];

    // B fragments for the whole K-tile (read once, phase 0)
#pragma unroll
    for (int n = 0; n < 4; ++n)
#pragma unroll
      for (int ks = 0; ks < 2; ++ks) {
        const int row = brow0 + n * 16 + frow;
        const int e = (row * 64 + ks * 32 + fk) ^ (((row >> 2) & 1) << 4);
        bf[n][ks] = *(const short8*)(Bcur + e);
      }

    // ph0: A m{0,1}; stage A-half0(u+1) -> other buf
    PHASE(0,
          if (u + 1 < NT) stage(gA, lda, kbeg + (u + 1) * 64, lds + nxt * 32768),
          );
    // ph1: A m{2,3}; stage A-half1(u+1)
    PHASE(2,
          if (u + 1 < NT) stage(gA + (size_t)128 * lda, lda, kbeg + (u + 1) * 64, lds + nxt * 32768 + 8192),
          );
    // ph2: A m{4,5}; stage B-half0(u+2) -> cur buf (B dead since ph0)
    PHASE(4,
          if (u + 2 < NT) stage(gB, ldb, kbeg + (u + 2) * 64, lds + cur * 32768 + 16384),
          );
    // ph3: A m{6,7}; stage B-half1(u+2); counted vmcnt at K-tile boundary
    PHASE(6,
          if (u + 2 < NT) stage(gB + (size_t)128 * ldb, ldb, kbeg + (u + 2) * 64, lds + cur * 32768 + 24576),
          if (u + 2 < NT) { asm volatile("s_waitcnt vmcnt(4)" ::: "memory"); }
          else            { asm volatile("s_waitcnt vmcnt(0)" ::: "memory"); } );
  }

  // ---- epilogue ----
#pragma unroll
  for (int m = 0; m < 8; ++m) {
#pragma unroll
    for (int n = 0; n < 4; ++n) {
      const int row0 = bm + wr * 128 + m * 16 + (lane >> 4) * 4;
      const int col  = bn + wc * 64 + n * 16 + (lane & 15);
      if constexpr (MODE == 0) {
        float* C; int ldc;
        if      (blockIdx.z == 0) { C = C0; ldc = ldc0; }
        else if (blockIdx.z == 1) { C = C1; ldc = ldc1; }
        else if (blockIdx.z == 2) { C = C2; ldc = ldc2; }
        else                      { C = C3; ldc = ldc3; }
#pragma unroll
        for (int j = 0; j < 4; ++j)
          C[(size_t)(row0 + j) * ldc + col] = acc[m][n][j] * alpha;
      } else {
        if (bn < 2048) {
#pragma unroll
          for (int j = 0; j < 4; ++j)
            Cqk[(size_t)(row0 + j) * ldqk + col] = f2bf(acc[m][n][j] * alpha);
        } else {
          ushort4 o;
          o.x = f2bf(acc[m][n][0] * alpha);
          o.y = f2bf(acc[m][n][1] * alpha);
          o.z = f2bf(acc[m][n][2] * alpha);
          o.w = f2bf(acc[m][n][3] * alpha);
          *(ushort4*)(CvT + (size_t)(col - 2048) * ldvt + row0) = o;
        }
      }
    }
  }
}

// ---------------- row softmax over S (fp32 [4096][4096]); writes bf16 P in place ----------------
__global__ __launch_bounds__(256) void softmax_rows(float* __restrict__ S) {
  const int row  = blockIdx.x;
  const int t    = threadIdx.x;
  const int lane = t & 63;
  const int wave = t >> 6;

  const float4* src = (const float4*)(S + (size_t)row * 4096);
  float4 v[4];
  float m = -3.0e38f;
#pragma unroll
  for (int i = 0; i < 4; ++i) {
    v[i] = src[t + 256 * i];
    m = fmaxf(m, fmaxf(fmaxf(v[i].x, v[i].y), fmaxf(v[i].z, v[i].w)));
  }
#pragma unroll
  for (int off = 1; off < 64; off <<= 1)
    m = fmaxf(m, __shfl_xor(m, off));

  __shared__ float red[4];
  if (lane == 0) red[wave] = m;
  __syncthreads();
  m = fmaxf(fmaxf(red[0], red[1]), fmaxf(red[2], red[3]));
  __syncthreads();

  float p[16];
  float s = 0.f;
#pragma unroll
  for (int i = 0; i < 4; ++i) {
    p[4 * i + 0] = __expf(v[i].x - m);
    p[4 * i + 1] = __expf(v[i].y - m);
    p[4 * i + 2] = __expf(v[i].z - m);
    p[4 * i + 3] = __expf(v[i].w - m);
    s += p[4 * i + 0] + p[4 * i + 1] + p[4 * i + 2] + p[4 * i + 3];
  }
#pragma unroll
  for (int off = 1; off < 64; off <<= 1)
    s += __shfl_xor(s, off);
  if (lane == 0) red[wave] = s;
  __syncthreads();
  s = red[0] + red[1] + red[2] + red[3];
  const float inv = 1.0f / s;

  unsigned short* dst = (unsigned short*)S + (size_t)row * 8192;
#pragma unroll
  for (int i = 0; i < 4; ++i) {
    ushort4 o;
    o.x = f2bf(p[4 * i + 0] * inv);
    o.y = f2bf(p[4 * i + 1] * inv);
    o.z = f2bf(p[4 * i + 2] * inv);
    o.w = f2bf(p[4 * i + 3] * inv);
    *(ushort4*)(dst + 4 * (t + 256 * i)) = o;
  }
}

// ---------------- combine split-K=4 partials: out += p1 + p2 + p3 ----------------
// out/p1: ld 1024; p2/p3: ld 4096 floats (live in the odd 8KB halves of S rows)
__global__ __launch_bounds__(256) void combine4(float* __restrict__ out,
                                                const float* __restrict__ p1,
                                                const float* __restrict__ p2,
                                                const float* __restrict__ p3) {
  const int r = blockIdx.x, c = threadIdx.x;
  float4 o = ((float4*)(out + (size_t)r * 1024))[c];
  float4 a = ((const float4*)(p1 + (size_t)r * 1024))[c];
  float4 b = ((const float4*)(p2 + (size_t)r * 4096))[c];
  float4 d = ((const float4*)(p3 + (size_t)r * 4096))[c];
  o.x += a.x + b.x + d.x;
  o.y += a.y + b.y + d.y;
  o.z += a.z + b.z + d.z;
  o.w += a.w + b.w + d.w;
  ((float4*)(out + (size_t)r * 1024))[c] = o;
}

// ---------------- launch ----------------
extern "C" void kernel_launch(void* const* d_in, const int* in_sizes, int n_in,
                              void* d_out, int out_size, void* d_ws, size_t ws_size,
                              hipStream_t stream) {
  const float* x  = (const float*)d_in[0];
  const float* Wq = (const float*)d_in[1];
  const float* Wk = (const float*)d_in[2];
  const float* Wv = (const float*)d_in[3];

  // ws layout (bytes):
  //   [0, 64M)   : S fp32 [4096][4096]; after softmax row r holds: P bf16 at [r*16K, r*16K+8K),
  //                ctx partial z=2 at [+8K,+12K), z=3 at [+12K,+16K)
  //   [64M, 80M) : QK bf16 [4096][2048] (q|k); dead after scores -> ctx partial z=1 fp32
  //   [80M, 88M) : vT bf16 [1024][4096]
  //   [88M, 96M) : xb bf16 [4096][1024]
  //   [96M,102M) : Wcat bf16 [3072][1024]
  char* ws = (char*)d_ws;
  float*          S     = (float*)ws;
  unsigned short* Pm    = (unsigned short*)ws;                // bf16 view, row stride 8192
  float*          Cp2   = (float*)(ws + 8192);                // ld 4096
  float*          Cp3   = (float*)(ws + 12288);               // ld 4096
  unsigned short* QK    = (unsigned short*)(ws + 67108864);
  float*          Cp1   = (float*)(ws + 67108864);            // ld 1024 (reuse after scores)
  unsigned short* vT    = (unsigned short*)(ws + 83886080);   // [1024][4096]
  unsigned short* xb    = (unsigned short*)(ws + 92274688);
  unsigned short* Wcat  = (unsigned short*)(ws + 100663296);

  cast_kernel<<<4096, 256, 0, stream>>>(x,  xb,            1048576);
  cast_kernel<<<1024, 256, 0, stream>>>(Wq, Wcat,           262144);
  cast_kernel<<<1024, 256, 0, stream>>>(Wk, Wcat + 1048576, 262144);
  cast_kernel<<<1024, 256, 0, stream>>>(Wv, Wcat + 2097152, 262144);

  // fused QKV: [4096][3072] = xb @ Wcat^T; q|k -> QK bf16, v -> vT (transposed)
  gemm8<2><<<dim3(12, 16, 1), 512, 0, stream>>>(
      xb, 1024, Wcat, 1024, 1024, 1.0f,
      nullptr, 0, nullptr, 0, nullptr, 0, nullptr, 0, QK, 2048, vT, 4096);

  // S = (q @ k^T) / 32  (fp32)
  gemm8<0><<<dim3(16, 16, 1), 512, 0, stream>>>(
      QK, 2048, QK + 1024, 2048, 1024, 0.03125f,
      S, 4096, nullptr, 0, nullptr, 0, nullptr, 0, nullptr, 0, nullptr, 0);

  softmax_rows<<<4096, 256, 0, stream>>>(S);

  // context = P @ vT^T, split-K=4; z=0 -> d_out, z=1..3 -> partials; then combine
  gemm8<0><<<dim3(4, 16, 4), 512, 0, stream>>>(
      Pm, 8192, vT, 4096, 1024, 1.0f,
      (float*)d_out, 1024, Cp1, 1024, Cp2, 4096, Cp3, 4096, nullptr, 0, nullptr, 0);
  combine4<<<4096, 256, 0, stream>>>((float*)d_out, Cp1, Cp2, Cp3);
}

// Round 4
// 165.302 us; speedup vs baseline: 1.5402x; 1.0381x over previous
//
#include <hip/hip_runtime.h>

typedef __attribute__((ext_vector_type(4))) float f32x4;
typedef __attribute__((ext_vector_type(8))) short short8;

__device__ __forceinline__ unsigned short f2bf(float f) {
  unsigned int u = __float_as_uint(f);
  u += 0x7fff + ((u >> 16) & 1);   // round-to-nearest-even
  return (unsigned short)(u >> 16);
}

// ---------------- cast fp32 -> bf16 (stored as ushort), 4 elems/thread ----------------
__global__ __launch_bounds__(256) void cast_kernel(const float* __restrict__ in,
                                                   unsigned short* __restrict__ out,
                                                   int n4) {
  int i = blockIdx.x * 256 + threadIdx.x;
  if (i >= n4) return;
  float4 v = ((const float4*)in)[i];
  ushort4 o;
  o.x = f2bf(v.x); o.y = f2bf(v.y); o.z = f2bf(v.z); o.w = f2bf(v.w);
  ((ushort4*)out)[i] = o;
}

// ======================= 256x256 8-phase NT GEMM =======================
// C[m][n] = alpha * sum_k A[m][k]*B[n][k].  8 waves (2M x 4N), BK=64, 128KB LDS dbuf.
// LDS swizzle: byte ^= (row&7)<<4 (elem ^= (row&7)<<3) — spreads the 16-row b128
// column read of a 128B-stride tile uniformly over all 32 banks (8 words/bank).
// Linear global_load_lds dest + inverse-swizzled global source (same involution).
// MODE 0: fp32 out, blockIdx.z in [0,4) selects K-chunk and (C0..C3, ldc0..3).
// MODE 2: QKV epilogue: cols [0,2048) -> bf16 Cqk; cols [2048,3072) -> transposed CvT.

#define PHASE(M0, STAGE, TAILWAIT)                                            \
  {                                                                           \
    _Pragma("unroll")                                                         \
    for (int mi = 0; mi < 2; ++mi) {                                          \
      _Pragma("unroll")                                                       \
      for (int ks = 0; ks < 2; ++ks) {                                        \
        const int row = (M0 + mi) * 16 + frow;                                \
        const int e = (row * 64 + ks * 32 + fk) ^ ((row & 7) << 3);           \
        af[mi][ks] = *(const short8*)(Acur + e);                              \
      }                                                                       \
    }                                                                         \
    STAGE;                                                                    \
    __builtin_amdgcn_s_barrier();                                             \
    asm volatile("s_waitcnt lgkmcnt(0)" ::: "memory");                        \
    __builtin_amdgcn_sched_barrier(0);                                        \
    __builtin_amdgcn_s_setprio(1);                                            \
    _Pragma("unroll")                                                         \
    for (int mi = 0; mi < 2; ++mi)                                            \
      _Pragma("unroll")                                                       \
      for (int n = 0; n < 4; ++n)                                             \
        _Pragma("unroll")                                                     \
        for (int ks = 0; ks < 2; ++ks)                                        \
          acc[M0 + mi][n] = __builtin_amdgcn_mfma_f32_16x16x32_bf16(          \
              af[mi][ks], bf[n][ks], acc[M0 + mi][n], 0, 0, 0);               \
    __builtin_amdgcn_s_setprio(0);                                            \
    __builtin_amdgcn_sched_barrier(0);                                        \
    TAILWAIT;                                                                 \
    __builtin_amdgcn_s_barrier();                                             \
  }

template <int MODE>
__global__ __launch_bounds__(512, 2) void gemm8(
    const unsigned short* __restrict__ A, int lda,
    const unsigned short* __restrict__ B, int ldb,
    int ksplit, float alpha,
    float* __restrict__ C0, int ldc0, float* __restrict__ C1, int ldc1,
    float* __restrict__ C2, int ldc2, float* __restrict__ C3, int ldc3,
    unsigned short* __restrict__ Cqk, int ldqk,
    unsigned short* __restrict__ CvT, int ldvt) {
  // 128 KB: buf b at b*32768 (ushorts); A halves at +0,+8192; B halves at +16384,+24576
  __shared__ __attribute__((aligned(16))) unsigned short lds[65536];

  const int t    = threadIdx.x;
  const int lane = t & 63;
  const int wave = t >> 6;
  const int wr   = wave >> 2;        // 0..1  (M)
  const int wc   = wave & 3;         // 0..3  (N)

  // XCD-aware bijective swizzle on the xy plane (nwg % 8 == 0 for all our grids)
  const int nx   = gridDim.x;
  const int nwg  = nx * gridDim.y;
  const int orig = blockIdx.y * nx + blockIdx.x;
  const int wg   = (orig & 7) * (nwg >> 3) + (orig >> 3);
  const int bm   = (wg / nx) * 256;
  const int bn   = (wg % nx) * 256;

  const int kbeg = blockIdx.z * ksplit;
  const int NT   = ksplit >> 6;

  const unsigned short* gA = A + (size_t)bm * lda;
  const unsigned short* gB = B + (size_t)bn * ldb;

  // stage one 128x64 half-tile: linear LDS dest (t*16B + j*8KB), inverse-swizzled source
  auto stage = [&](const unsigned short* gbase, int ld, int k0, unsigned short* dst) {
#pragma unroll
    for (int j = 0; j < 2; ++j) {
      const int de = t * 8 + j * 4096;                 // dest elem within half (linear)
      const int se = de ^ (((de >> 6) & 7) << 3);      // pre-swizzled source elem
      __builtin_amdgcn_global_load_lds(
          (const __attribute__((address_space(1))) void*)(gbase + (size_t)(se >> 6) * ld + k0 + (se & 63)),
          (__attribute__((address_space(3))) void*)(dst + de),
          16, 0, 0);
    }
  };

  f32x4 acc[8][4];
#pragma unroll
  for (int i = 0; i < 8; ++i)
#pragma unroll
    for (int j = 0; j < 4; ++j)
      acc[i][j] = (f32x4){0.f, 0.f, 0.f, 0.f};

  const int frow = lane & 15;
  const int fk   = (lane >> 4) * 8;

  // ---- prologue: K-tile 0 (A0,A1,B0,B1) + K-tile 1's B halves; leave B(1) in flight ----
  stage(gA,                     lda, kbeg, lds);
  stage(gA + (size_t)128 * lda, lda, kbeg, lds + 8192);
  stage(gB,                     ldb, kbeg, lds + 16384);
  stage(gB + (size_t)128 * ldb, ldb, kbeg, lds + 24576);
  if (NT > 1) {
    stage(gB,                     ldb, kbeg + 64, lds + 32768 + 16384);
    stage(gB + (size_t)128 * ldb, ldb, kbeg + 64, lds + 32768 + 24576);
    asm volatile("s_waitcnt vmcnt(4)" ::: "memory");
  } else {
    asm volatile("s_waitcnt vmcnt(0)" ::: "memory");
  }
  __builtin_amdgcn_sched_barrier(0);
  __builtin_amdgcn_s_barrier();

  for (int u = 0; u < NT; ++u) {
    const int cur = u & 1, nxt = cur ^ 1;
    const unsigned short* Acur = lds + cur * 32768 + wr * 8192;
    const unsigned short* Bcur = lds + cur * 32768 + 16384 + (wc >> 1) * 8192;
    const int brow0 = (wc & 1) * 64;

    short8 bf[4][2];
    short8 af[2][2];

    // B fragments for the whole K-tile (read once, phase 0)
#pragma unroll
    for (int n = 0; n < 4; ++n)
#pragma unroll
      for (int ks = 0; ks < 2; ++ks) {
        const int row = brow0 + n * 16 + frow;
        const int e = (row * 64 + ks * 32 + fk) ^ ((row & 7) << 3);
        bf[n][ks] = *(const short8*)(Bcur + e);
      }

    // ph0: A m{0,1}; stage A-half0(u+1) -> other buf
    PHASE(0,
          if (u + 1 < NT) stage(gA, lda, kbeg + (u + 1) * 64, lds + nxt * 32768),
          );
    // ph1: A m{2,3}; stage A-half1(u+1)
    PHASE(2,
          if (u + 1 < NT) stage(gA + (size_t)128 * lda, lda, kbeg + (u + 1) * 64, lds + nxt * 32768 + 8192),
          );
    // ph2: A m{4,5}; stage B-half0(u+2) -> cur buf (B dead since ph0)
    PHASE(4,
          if (u + 2 < NT) stage(gB, ldb, kbeg + (u + 2) * 64, lds + cur * 32768 + 16384),
          );
    // ph3: A m{6,7}; stage B-half1(u+2); counted vmcnt at K-tile boundary
    PHASE(6,
          if (u + 2 < NT) stage(gB + (size_t)128 * ldb, ldb, kbeg + (u + 2) * 64, lds + cur * 32768 + 24576),
          if (u + 2 < NT) { asm volatile("s_waitcnt vmcnt(4)" ::: "memory"); }
          else            { asm volatile("s_waitcnt vmcnt(0)" ::: "memory"); } );
  }

  // ---- epilogue ----
#pragma unroll
  for (int m = 0; m < 8; ++m) {
#pragma unroll
    for (int n = 0; n < 4; ++n) {
      const int row0 = bm + wr * 128 + m * 16 + (lane >> 4) * 4;
      const int col  = bn + wc * 64 + n * 16 + (lane & 15);
      if constexpr (MODE == 0) {
        float* C; int ldc;
        if      (blockIdx.z == 0) { C = C0; ldc = ldc0; }
        else if (blockIdx.z == 1) { C = C1; ldc = ldc1; }
        else if (blockIdx.z == 2) { C = C2; ldc = ldc2; }
        else                      { C = C3; ldc = ldc3; }
#pragma unroll
        for (int j = 0; j < 4; ++j)
          C[(size_t)(row0 + j) * ldc + col] = acc[m][n][j] * alpha;
      } else {
        if (bn < 2048) {
#pragma unroll
          for (int j = 0; j < 4; ++j)
            Cqk[(size_t)(row0 + j) * ldqk + col] = f2bf(acc[m][n][j] * alpha);
        } else {
          ushort4 o;
          o.x = f2bf(acc[m][n][0] * alpha);
          o.y = f2bf(acc[m][n][1] * alpha);
          o.z = f2bf(acc[m][n][2] * alpha);
          o.w = f2bf(acc[m][n][3] * alpha);
          *(ushort4*)(CvT + (size_t)(col - 2048) * ldvt + row0) = o;
        }
      }
    }
  }
}

// ---------------- row softmax over S (fp32 [4096][4096]); writes bf16 P in place ----------------
__global__ __launch_bounds__(256) void softmax_rows(float* __restrict__ S) {
  const int row  = blockIdx.x;
  const int t    = threadIdx.x;
  const int lane = t & 63;
  const int wave = t >> 6;

  const float4* src = (const float4*)(S + (size_t)row * 4096);
  float4 v[4];
  float m = -3.0e38f;
#pragma unroll
  for (int i = 0; i < 4; ++i) {
    v[i] = src[t + 256 * i];
    m = fmaxf(m, fmaxf(fmaxf(v[i].x, v[i].y), fmaxf(v[i].z, v[i].w)));
  }
#pragma unroll
  for (int off = 1; off < 64; off <<= 1)
    m = fmaxf(m, __shfl_xor(m, off));

  __shared__ float red[4];
  if (lane == 0) red[wave] = m;
  __syncthreads();
  m = fmaxf(fmaxf(red[0], red[1]), fmaxf(red[2], red[3]));
  __syncthreads();

  float p[16];
  float s = 0.f;
#pragma unroll
  for (int i = 0; i < 4; ++i) {
    p[4 * i + 0] = __expf(v[i].x - m);
    p[4 * i + 1] = __expf(v[i].y - m);
    p[4 * i + 2] = __expf(v[i].z - m);
    p[4 * i + 3] = __expf(v[i].w - m);
    s += p[4 * i + 0] + p[4 * i + 1] + p[4 * i + 2] + p[4 * i + 3];
  }
#pragma unroll
  for (int off = 1; off < 64; off <<= 1)
    s += __shfl_xor(s, off);
  if (lane == 0) red[wave] = s;
  __syncthreads();
  s = red[0] + red[1] + red[2] + red[3];
  const float inv = 1.0f / s;

  unsigned short* dst = (unsigned short*)S + (size_t)row * 8192;
#pragma unroll
  for (int i = 0; i < 4; ++i) {
    ushort4 o;
    o.x = f2bf(p[4 * i + 0] * inv);
    o.y = f2bf(p[4 * i + 1] * inv);
    o.z = f2bf(p[4 * i + 2] * inv);
    o.w = f2bf(p[4 * i + 3] * inv);
    *(ushort4*)(dst + 4 * (t + 256 * i)) = o;
  }
}

// ---------------- combine split-K=4 partials: out += p1 + p2 + p3 ----------------
// out/p1: ld 1024; p2/p3: ld 4096 floats (live in the odd 8KB halves of S rows)
__global__ __launch_bounds__(256) void combine4(float* __restrict__ out,
                                                const float* __restrict__ p1,
                                                const float* __restrict__ p2,
                                                const float* __restrict__ p3) {
  const int r = blockIdx.x, c = threadIdx.x;
  float4 o = ((float4*)(out + (size_t)r * 1024))[c];
  float4 a = ((const float4*)(p1 + (size_t)r * 1024))[c];
  float4 b = ((const float4*)(p2 + (size_t)r * 4096))[c];
  float4 d = ((const float4*)(p3 + (size_t)r * 4096))[c];
  o.x += a.x + b.x + d.x;
  o.y += a.y + b.y + d.y;
  o.z += a.z + b.z + d.z;
  o.w += a.w + b.w + d.w;
  ((float4*)(out + (size_t)r * 1024))[c] = o;
}

// ---------------- launch ----------------
extern "C" void kernel_launch(void* const* d_in, const int* in_sizes, int n_in,
                              void* d_out, int out_size, void* d_ws, size_t ws_size,
                              hipStream_t stream) {
  const float* x  = (const float*)d_in[0];
  const float* Wq = (const float*)d_in[1];
  const float* Wk = (const float*)d_in[2];
  const float* Wv = (const float*)d_in[3];

  // ws layout (bytes):
  //   [0, 64M)   : S fp32 [4096][4096]; after softmax row r holds: P bf16 at [r*16K, r*16K+8K),
  //                ctx partial z=2 at [+8K,+12K), z=3 at [+12K,+16K)
  //   [64M, 80M) : QK bf16 [4096][2048] (q|k); dead after scores -> ctx partial z=1 fp32
  //   [80M, 88M) : vT bf16 [1024][4096]
  //   [88M, 96M) : xb bf16 [4096][1024]
  //   [96M,102M) : Wcat bf16 [3072][1024]
  char* ws = (char*)d_ws;
  float*          S     = (float*)ws;
  unsigned short* Pm    = (unsigned short*)ws;                // bf16 view, row stride 8192
  float*          Cp2   = (float*)(ws + 8192);                // ld 4096
  float*          Cp3   = (float*)(ws + 12288);               // ld 4096
  unsigned short* QK    = (unsigned short*)(ws + 67108864);
  float*          Cp1   = (float*)(ws + 67108864);            // ld 1024 (reuse after scores)
  unsigned short* vT    = (unsigned short*)(ws + 83886080);   // [1024][4096]
  unsigned short* xb    = (unsigned short*)(ws + 92274688);
  unsigned short* Wcat  = (unsigned short*)(ws + 100663296);

  cast_kernel<<<4096, 256, 0, stream>>>(x,  xb,            1048576);
  cast_kernel<<<1024, 256, 0, stream>>>(Wq, Wcat,           262144);
  cast_kernel<<<1024, 256, 0, stream>>>(Wk, Wcat + 1048576, 262144);
  cast_kernel<<<1024, 256, 0, stream>>>(Wv, Wcat + 2097152, 262144);

  // fused QKV: [4096][3072] = xb @ Wcat^T; q|k -> QK bf16, v -> vT (transposed)
  gemm8<2><<<dim3(12, 16, 1), 512, 0, stream>>>(
      xb, 1024, Wcat, 1024, 1024, 1.0f,
      nullptr, 0, nullptr, 0, nullptr, 0, nullptr, 0, QK, 2048, vT, 4096);

  // S = (q @ k^T) / 32  (fp32)
  gemm8<0><<<dim3(16, 16, 1), 512, 0, stream>>>(
      QK, 2048, QK + 1024, 2048, 1024, 0.03125f,
      S, 4096, nullptr, 0, nullptr, 0, nullptr, 0, nullptr, 0, nullptr, 0);

  softmax_rows<<<4096, 256, 0, stream>>>(S);

  // context = P @ vT^T, split-K=4; z=0 -> d_out, z=1..3 -> partials; then combine
  gemm8<0><<<dim3(4, 16, 4), 512, 0, stream>>>(
      Pm, 8192, vT, 4096, 1024, 1.0f,
      (float*)d_out, 1024, Cp1, 1024, Cp2, 4096, Cp3, 4096, nullptr, 0, nullptr, 0);
  combine4<<<4096, 256, 0, stream>>>((float*)d_out, Cp1, Cp2, Cp3);
}